// Round 2
// baseline (224.643 us; speedup 1.0000x reference)
//
#include <hip/hip_runtime.h>
#include <hip/hip_bf16.h>
#include <stdint.h>

typedef __bf16 bf16;
typedef bf16 bf16x4 __attribute__((ext_vector_type(4)));
typedef bf16 bf16x8 __attribute__((ext_vector_type(8)));
typedef float f32x4 __attribute__((ext_vector_type(4)));

#define LOGSQRT2PI 0.9189385332046727f

__device__ __forceinline__ void gload_lds16(const void* g, void* l) {
    __builtin_amdgcn_global_load_lds((__attribute__((address_space(1))) void*)g,
                                     (__attribute__((address_space(3))) void*)l,
                                     16, 0, 0);
}

// ---- zero the two scalar accumulators in d_out ----
__global__ void k_zero2(float* p) {
    if (threadIdx.x < 2) p[threadIdx.x] = 0.0f;
}

// ---- weight prep: W = mu + (1e-6+softplus(p))*eps ; write Wt[n][k] bf16 ;
// ---- accumulate lqw/lpw into osc[0]/osc[1] ----
__global__ void k_prep(const float* __restrict__ mu, const float* __restrict__ p,
                       const float* __restrict__ eps, bf16* __restrict__ Wt,
                       int K, int N, int Npad, float* __restrict__ osc) {
    int total = K * Npad;
    float lqw = 0.0f, lpw = 0.0f;
    for (int idx = blockIdx.x * blockDim.x + threadIdx.x; idx < total;
         idx += gridDim.x * blockDim.x) {
        int k = idx / Npad;
        int n = idx - k * Npad;
        float w = 0.0f;
        if (n < N) {
            int src = k * N + n;
            float m = mu[src];
            float e = eps[src];
            float sd = 1e-6f + log1pf(expf(p[src]));
            w = m + sd * e;
            float z = (w - m) / sd;
            lqw += -LOGSQRT2PI - logf(sd) - 0.5f * z * z;
            lpw += -LOGSQRT2PI - 0.5f * w * w;
        }
        Wt[n * K + k] = (bf16)w;
    }
    #pragma unroll
    for (int off = 32; off; off >>= 1) {
        lqw += __shfl_down(lqw, off);
        lpw += __shfl_down(lpw, off);
    }
    if ((threadIdx.x & 63) == 0) {
        atomicAdd(&osc[0], lqw);
        atomicAdd(&osc[1], lpw);
    }
}

// ---- x fp32 -> bf16 ----
__global__ void k_cvt(const float4* __restrict__ in, bf16x4* __restrict__ out, int n4) {
    int stride = gridDim.x * blockDim.x;
    for (int i = blockIdx.x * blockDim.x + threadIdx.x; i < n4; i += stride) {
        float4 v = in[i];
        bf16x4 o;
        o[0] = (bf16)v.x; o[1] = (bf16)v.y; o[2] = (bf16)v.z; o[3] = (bf16)v.w;
        out[i] = o;
    }
}

// ============================================================================
// 256x256 8-phase pipelined GEMM:  C[M][512] = A[M][512] @ Bt[512][512]^T
// 8 waves (2M x 4N), BK=64 (2 x ks-halves of 32), double-buffered 128KiB LDS.
// LDS layout is FRAGMENT-ordered (chunk = 1024B = one wave-frag read), filled
// by global_load_lds with a pre-permuted global source -> ds_read_b128 of a
// contiguous 1KB region per wave = zero bank conflicts.
//   chunk(ii,ks) at elems (ii*2+ks)*512 ; within: lane l holds 8 elems at l*8
//   A: lane l of chunk(ii,ks) = A[row = ii*16 + (l&15)][k = ks*32 + (l>>4)*8 ..]
//   B identical with Bt rows = C cols.
// Staging unit = (matrix, ks) quarter: 16KB = 2 gload_lds16 per thread.
//   tile T phases: ph0 stage (T+1).A-ks1, ph1 (T+1).B-ks1 (other buffer),
//                  ph2 stage (T+2).A-ks0, ph3 (T+2).B-ks0 (current buffer,
//                  whose ks0 chunks are dead after ph1).
// Counted waits: vmcnt(8) before ph1-end and ph3-end barriers (tail 8->4->0).
// ============================================================================
template<bool RELU>
__global__ __launch_bounds__(512, 2)
void k_gemm256(const bf16* __restrict__ A, const bf16* __restrict__ Bt,
               bf16* __restrict__ C) {
    __shared__ __align__(16) bf16 Alds[32768];   // 64KB: 2 buf x 16 chunks x 2 ks x 512
    __shared__ __align__(16) bf16 Blds[32768];   // 64KB

    const int tid = threadIdx.x;
    const int l   = tid & 63;
    const int w   = tid >> 6;        // wave 0..7
    const int wm  = w >> 2;          // 0..1  (M half of the tile)
    const int wn  = w & 3;           // 0..3  (N quarter)
    const int l8  = l * 8;           // lane elem offset within a chunk

    // bijective XCD swizzle: 512 blocks, 64 per XCD -> (m,n) pairs co-located
    const int bid     = blockIdx.x;
    const int logical = (bid & 7) * 64 + (bid >> 3);
    const long bm = (long)(logical >> 1) * 256;
    const int  bn = (logical & 1) * 256;

    // staging source bases: thread covers chunk ii = n*8 + w (n=inst 0/1)
    // row = ii*16 + (l&15), kelem = ks*32 + (l>>4)*8
    const bf16* Asrc = A  + (bm + w * 16 + (l & 15)) * 512 + ((l >> 4) * 8);
    const bf16* Bsrc = Bt + ((long)bn + w * 16 + (l & 15)) * 512 + ((l >> 4) * 8);

    #define STAGE(LDS, BASE, TT, KS, BUF) do {                                   \
        gload_lds16((BASE) + (TT) * 64 + (KS) * 32,                              \
                    &LDS[(BUF) * 16384 + ((w) * 2 + (KS)) * 512 + l8]);          \
        gload_lds16((BASE) + 65536 + (TT) * 64 + (KS) * 32,                      \
                    &LDS[(BUF) * 16384 + ((8 + w) * 2 + (KS)) * 512 + l8]);      \
    } while (0)

    f32x4 acc[8][4];
    #pragma unroll
    for (int i = 0; i < 8; i++)
        #pragma unroll
        for (int j = 0; j < 4; j++) acc[i][j] = (f32x4){0.f, 0.f, 0.f, 0.f};

    bf16x8 afr[4], bfr[4];

    #define LOADA(IH, KS) {                                                      \
        _Pragma("unroll")                                                        \
        for (int i = 0; i < 4; i++)                                              \
            afr[i] = *(const bf16x8*)&Alds[buf * 16384 +                         \
                     ((wm * 8 + (IH) * 4 + i) * 2 + (KS)) * 512 + l8]; }
    #define LOADB(KS) {                                                          \
        _Pragma("unroll")                                                        \
        for (int j = 0; j < 4; j++)                                              \
            bfr[j] = *(const bf16x8*)&Blds[buf * 16384 +                         \
                     ((wn * 4 + j) * 2 + (KS)) * 512 + l8]; }
    #define MFMA16(IH) {                                                         \
        _Pragma("unroll")                                                        \
        for (int i = 0; i < 4; i++)                                              \
            _Pragma("unroll")                                                    \
            for (int j = 0; j < 4; j++)                                          \
                acc[(IH) * 4 + i][j] = __builtin_amdgcn_mfma_f32_16x16x32_bf16(  \
                    afr[i], bfr[j], acc[(IH) * 4 + i][j], 0, 0, 0); }

    // ---- prologue: tile0 fully + tile1 ks0 ----
    STAGE(Alds, Asrc, 0, 0, 0);
    STAGE(Blds, Bsrc, 0, 0, 0);
    STAGE(Alds, Asrc, 0, 1, 0);
    STAGE(Blds, Bsrc, 0, 1, 0);
    STAGE(Alds, Asrc, 1, 0, 1);
    STAGE(Blds, Bsrc, 1, 0, 1);
    asm volatile("s_waitcnt vmcnt(4)" ::: "memory");   // tile0 done, tile1.ks0 in flight
    __builtin_amdgcn_s_barrier();

    for (int T = 0; T < 8; ++T) {
        const int buf = T & 1;
        const int nb  = buf ^ 1;
        // ---- phase 0: ks0, ihalf0 ----
        LOADB(0);
        LOADA(0, 0);
        if (T < 7) STAGE(Alds, Asrc, T + 1, 1, nb);
        __builtin_amdgcn_s_barrier();
        __builtin_amdgcn_s_setprio(1);
        MFMA16(0);
        __builtin_amdgcn_s_setprio(0);
        __builtin_amdgcn_s_barrier();
        // ---- phase 1: ks0, ihalf1 ----
        LOADA(1, 0);
        if (T < 7) STAGE(Blds, Bsrc, T + 1, 1, nb);
        __builtin_amdgcn_s_barrier();
        __builtin_amdgcn_s_setprio(1);
        MFMA16(1);
        __builtin_amdgcn_s_setprio(0);
        if (T < 7) { asm volatile("s_waitcnt vmcnt(8)" ::: "memory"); }
        else       { asm volatile("s_waitcnt vmcnt(0)" ::: "memory"); }
        __builtin_amdgcn_s_barrier();
        // ---- phase 2: ks1, ihalf0 ----
        LOADB(1);
        LOADA(0, 1);
        if (T < 6) STAGE(Alds, Asrc, T + 2, 0, buf);
        __builtin_amdgcn_s_barrier();
        __builtin_amdgcn_s_setprio(1);
        MFMA16(0);
        __builtin_amdgcn_s_setprio(0);
        __builtin_amdgcn_s_barrier();
        // ---- phase 3: ks1, ihalf1 ----
        LOADA(1, 1);
        if (T < 6) STAGE(Blds, Bsrc, T + 2, 0, buf);
        __builtin_amdgcn_s_barrier();
        __builtin_amdgcn_s_setprio(1);
        MFMA16(1);
        __builtin_amdgcn_s_setprio(0);
        if (T < 6)       { asm volatile("s_waitcnt vmcnt(8)" ::: "memory"); }
        else if (T == 6) { asm volatile("s_waitcnt vmcnt(4)" ::: "memory"); }
        __builtin_amdgcn_s_barrier();
    }

    // ---- epilogue: C/D layout col = lane&15, row = (lane>>4)*4 + q ----
    #pragma unroll
    for (int ih = 0; ih < 8; ih++) {
        #pragma unroll
        for (int j = 0; j < 4; j++) {
            #pragma unroll
            for (int q = 0; q < 4; q++) {
                long row = bm + wm * 128 + ih * 16 + (l >> 4) * 4 + q;
                int  col = bn + wn * 64 + j * 16 + (l & 15);
                float v = acc[ih][j][q];
                if (RELU) v = fmaxf(v, 0.0f);
                C[row * 512 + col] = (bf16)v;
            }
        }
    }
    #undef STAGE
    #undef LOADA
    #undef LOADB
    #undef MFMA16
}

// ---- final layer: C[M][10] fp32 = A[M][512] @ Bt[16][512]^T ----
__global__ __launch_bounds__(256)
void k_gemm_out(const bf16* __restrict__ A, const bf16* __restrict__ Bt,
                float* __restrict__ C) {
    __shared__ bf16 Bs[16 * 520];
    const int tid = threadIdx.x;
    #pragma unroll
    for (int c = tid; c < 1024; c += 256) {
        int n = c >> 6;
        int k = (c & 63) * 8;
        *(bf16x8*)&Bs[n * 520 + k] = *(const bf16x8*)&Bt[n * 512 + k];
    }
    __syncthreads();
    const int lane = tid & 63, wave = tid >> 6;
    const long m0 = (long)blockIdx.x * 64 + wave * 16;
    const int r  = lane & 15;
    const int kh = (lane >> 4) * 8;
    const bf16* ap = A + (m0 + r) * 512 + kh;
    f32x4 acc = (f32x4){0.f, 0.f, 0.f, 0.f};
    #pragma unroll
    for (int kt = 0; kt < 512; kt += 32) {
        bf16x8 a = *(const bf16x8*)(ap + kt);
        bf16x8 b = *(const bf16x8*)&Bs[r * 520 + kt + kh];
        acc = __builtin_amdgcn_mfma_f32_16x16x32_bf16(a, b, acc, 0, 0, 0);
    }
    if (r < 10) {
        #pragma unroll
        for (int q = 0; q < 4; q++) {
            long row = m0 + (lane >> 4) * 4 + q;
            C[row * 10 + r] = acc[q];
        }
    }
}

extern "C" void kernel_launch(void* const* d_in, const int* in_sizes, int n_in,
                              void* d_out, int out_size, void* d_ws, size_t ws_size,
                              hipStream_t stream) {
    const float* x   = (const float*)d_in[0];
    const float* mu1 = (const float*)d_in[1];
    const float* p1  = (const float*)d_in[2];
    const float* e1  = (const float*)d_in[3];
    const float* mu2 = (const float*)d_in[4];
    const float* p2  = (const float*)d_in[5];
    const float* e2  = (const float*)d_in[6];
    const float* mu3 = (const float*)d_in[7];
    const float* p3  = (const float*)d_in[8];
    const float* e3  = (const float*)d_in[9];
    float* out = (float*)d_out;

    const int B = 65536, D = 512, DO = 10, DOP = 16;

    char* ws = (char*)d_ws;
    bf16* Wt1 = (bf16*)(ws);
    bf16* Wt2 = (bf16*)(ws + 524288);
    bf16* Wt3 = (bf16*)(ws + 1048576);
    bf16* xb  = (bf16*)(ws + 1114112);
    bf16* h1  = (bf16*)(ws + 1114112 + 67108864);
    bf16* h2  = xb;

    float* osc = out + (long)B * DO;

    hipLaunchKernelGGL(k_zero2, dim3(1), dim3(64), 0, stream, osc);
    hipLaunchKernelGGL(k_prep, dim3(256), dim3(256), 0, stream, mu1, p1, e1, Wt1, D, D,  D,   osc);
    hipLaunchKernelGGL(k_prep, dim3(256), dim3(256), 0, stream, mu2, p2, e2, Wt2, D, D,  D,   osc);
    hipLaunchKernelGGL(k_prep, dim3(16),  dim3(256), 0, stream, mu3, p3, e3, Wt3, D, DO, DOP, osc);
    hipLaunchKernelGGL(k_cvt, dim3(2048), dim3(256), 0, stream,
                       (const float4*)x, (bf16x4*)xb, B * D / 4);
    hipLaunchKernelGGL((k_gemm256<true>), dim3(512), dim3(512), 0, stream, xb, Wt1, h1);
    hipLaunchKernelGGL((k_gemm256<true>), dim3(512), dim3(512), 0, stream, h1, Wt2, h2);
    hipLaunchKernelGGL(k_gemm_out, dim3(B / 64), dim3(256), 0, stream, h2, Wt3, out);
}

// Round 3
// 198.890 us; speedup vs baseline: 1.1295x; 1.1295x over previous
//
#include <hip/hip_runtime.h>
#include <hip/hip_bf16.h>
#include <stdint.h>

typedef __bf16 bf16;
typedef bf16 bf16x8 __attribute__((ext_vector_type(8)));
typedef float f32x4 __attribute__((ext_vector_type(4)));

#define LOGSQRT2PI 0.9189385332046727f

__device__ __forceinline__ void gload_lds16(const void* g, void* l) {
    __builtin_amdgcn_global_load_lds((__attribute__((address_space(1))) void*)g,
                                     (__attribute__((address_space(3))) void*)l,
                                     16, 0, 0);
}

// ---- zero d_out (y region + the two scalar accumulators) ----
__global__ void k_zero(float* p, int n) {
    int stride = gridDim.x * blockDim.x;
    for (int i = blockIdx.x * blockDim.x + threadIdx.x; i < n; i += stride) p[i] = 0.f;
}

// ---- weight prep: W = mu + (1e-6+softplus(p))*eps ; write Wt[n][k] bf16 ;
// ---- accumulate lqw/lpw into osc[0]/osc[1] ----
__global__ void k_prep(const float* __restrict__ mu, const float* __restrict__ p,
                       const float* __restrict__ eps, bf16* __restrict__ Wt,
                       int K, int N, int Npad, float* __restrict__ osc) {
    int total = K * Npad;
    float lqw = 0.0f, lpw = 0.0f;
    for (int idx = blockIdx.x * blockDim.x + threadIdx.x; idx < total;
         idx += gridDim.x * blockDim.x) {
        int k = idx / Npad;
        int n = idx - k * Npad;
        float w = 0.0f;
        if (n < N) {
            int src = k * N + n;
            float m = mu[src];
            float e = eps[src];
            float sd = 1e-6f + log1pf(expf(p[src]));
            w = m + sd * e;
            float z = (w - m) / sd;
            lqw += -LOGSQRT2PI - logf(sd) - 0.5f * z * z;
            lpw += -LOGSQRT2PI - 0.5f * w * w;
        }
        Wt[n * K + k] = (bf16)w;
    }
    #pragma unroll
    for (int off = 32; off; off >>= 1) {
        lqw += __shfl_down(lqw, off);
        lpw += __shfl_down(lpw, off);
    }
    if ((threadIdx.x & 63) == 0) {
        atomicAdd(&osc[0], lqw);
        atomicAdd(&osc[1], lpw);
    }
}

// ============================================================================
// Shared 256x256 main-loop geometry (both GEMMs):
//   8 waves (2M x 4N), BK=64 (2 ks-halves of 32), double-buffered LDS.
//   LDS chunk = 1024B = one wave ds_read_b128 region, fragment-ordered:
//   chunk(rowgroup rg 0..15, ks) at elems ((rg)*2+ks)*512, lane l holds
//   A[row=rg*16+(l&15)][k=ks*32+(l>>4)*8 ..+8] at chunk+l*8.  Conflict-free
//   (contiguous 1KB per wave access).
// Epilogue LDS bounce: tile [256 rows][256 cols] bf16, 16B-chunk swizzle
//   phys_chunk = cc ^ (row&7).  Write side: 4 rows x 16 cols per inst ->
//   rows differ in (row&7) -> chunks spread across all 32 banks.  Read side:
//   b128, lanes = 2 rows x 32 chunks -> 8 lanes/bank-quad, even. Both clean.
// ============================================================================

#define MFMA16(IH) {                                                           \
    _Pragma("unroll")                                                          \
    for (int i = 0; i < 4; i++)                                                \
        _Pragma("unroll")                                                      \
        for (int j = 0; j < 4; j++)                                            \
            acc[(IH) * 4 + i][j] = __builtin_amdgcn_mfma_f32_16x16x32_bf16(    \
                afr[i], bfr[j], acc[(IH) * 4 + i][j], 0, 0, 0); }

#define LOADA(IH, KS) { _Pragma("unroll")                                      \
    for (int i = 0; i < 4; i++)                                                \
        afr[i] = *(const bf16x8*)&LDSe[buf * 16384 +                           \
                 ((wm * 8 + (IH) * 4 + i) * 2 + (KS)) * 512 + l8]; }
#define LOADB(KS) { _Pragma("unroll")                                          \
    for (int j = 0; j < 4; j++)                                                \
        bfr[j] = *(const bf16x8*)&LDSe[32768 + buf * 16384 +                   \
                 ((wn * 4 + j) * 2 + (KS)) * 512 + l8]; }

// ---- Layer 1: h1 = relu(x @ W1), x fp32 streamed through regs -> bf16 ----
__global__ __launch_bounds__(512, 2)
void k_l1(const float* __restrict__ X, const bf16* __restrict__ Bt,
          bf16* __restrict__ C) {
    __shared__ __align__(16) bf16 LDSe[65536];   // A:[0,32768) B:[32768,65536)
    const int tid = threadIdx.x;
    const int l = tid & 63;
    const int w = tid >> 6;
    const int wm = w >> 2, wn = w & 3;
    const int l8 = l * 8;

    const int bid = blockIdx.x;
    const int logical = (bid & 7) * 64 + (bid >> 3);   // 512 % 8 == 0: bijective
    const long bm = (long)(logical >> 1) * 256;
    const int  bn = (logical & 1) * 256;

    const float* Asrc = X + (bm + w * 16 + (l & 15)) * 512 + ((l >> 4) * 8);
    const bf16*  Bsrc = Bt + ((long)bn + w * 16 + (l & 15)) * 512 + ((l >> 4) * 8);

    #define BSTAGE(TT, KS, BUF) do {                                           \
        gload_lds16(Bsrc + (TT) * 64 + (KS) * 32,                              \
                    &LDSe[32768 + (BUF) * 16384 + ((w) * 2 + (KS)) * 512 + l8]);\
        gload_lds16(Bsrc + 65536 + (TT) * 64 + (KS) * 32,                      \
                    &LDSe[32768 + (BUF) * 16384 + ((8 + w) * 2 + (KS)) * 512 + l8]);\
    } while (0)

    float4 ar[8];   // prefetched A fp32: [ii(2)][ks(2)][half(2)]
    #define AISSUE(TT) do {                                                    \
        _Pragma("unroll")                                                      \
        for (int ii = 0; ii < 2; ii++)                                         \
            _Pragma("unroll")                                                  \
            for (int ks = 0; ks < 2; ks++) {                                   \
                const float* s = Asrc + ii * (128 * 512) + (TT) * 64 + ks * 32;\
                ar[ii * 4 + ks * 2 + 0] = *(const float4*)(s);                 \
                ar[ii * 4 + ks * 2 + 1] = *(const float4*)(s + 4);             \
            }                                                                  \
        asm volatile("" ::: "memory");  /* pin issue position */               \
    } while (0)
    #define AWRITE(BUF) do {                                                   \
        _Pragma("unroll")                                                      \
        for (int ii = 0; ii < 2; ii++)                                         \
            _Pragma("unroll")                                                  \
            for (int ks = 0; ks < 2; ks++) {                                   \
                bf16x8 v;                                                      \
                _Pragma("unroll")                                              \
                for (int e = 0; e < 4; e++) {                                  \
                    v[e]     = (bf16)ar[ii * 4 + ks * 2 + 0][e];               \
                    v[e + 4] = (bf16)ar[ii * 4 + ks * 2 + 1][e];               \
                }                                                              \
                *(bf16x8*)&LDSe[(BUF) * 16384 + ((ii * 8 + w) * 2 + ks) * 512 + l8] = v; \
            }                                                                  \
    } while (0)

    f32x4 acc[8][4];
    #pragma unroll
    for (int i = 0; i < 8; i++)
        #pragma unroll
        for (int j = 0; j < 4; j++) acc[i][j] = (f32x4){0.f, 0.f, 0.f, 0.f};
    bf16x8 afr[4], bfr[4];

    // prologue: B before A so the first A-reg wait drains tile0's B loads
    BSTAGE(0, 0, 0); BSTAGE(0, 1, 0); BSTAGE(1, 0, 1);
    AISSUE(0);
    AWRITE(0);                       // reg-dep wait drains all older B gloads
    AISSUE(1);
    asm volatile("s_waitcnt lgkmcnt(0)" ::: "memory");
    __builtin_amdgcn_s_barrier();

    for (int T = 0; T < 8; ++T) {
        const int buf = T & 1, nb = buf ^ 1;
        // ph0: A(T+1) issue + compute ks0/ihalf0
        if (T < 7) AISSUE(T + 1);
        LOADB(0); LOADA(0, 0);
        __builtin_amdgcn_s_barrier();
        __builtin_amdgcn_s_setprio(1); MFMA16(0); __builtin_amdgcn_s_setprio(0);
        __builtin_amdgcn_s_barrier();
        // ph1: ks0/ihalf1 + stage B(T+1,ks1)->nb
        LOADA(1, 0);
        if (T < 7) BSTAGE(T + 1, 1, nb);
        __builtin_amdgcn_s_barrier();
        __builtin_amdgcn_s_setprio(1); MFMA16(1); __builtin_amdgcn_s_setprio(0);
        __builtin_amdgcn_s_barrier();
        // ph2: cvt+write A(T+1)->nb (its reg wait drains every B load issued
        // through iteration T-1, which covers everything read this phase)
        if (T < 7) AWRITE(nb);
        else asm volatile("s_waitcnt vmcnt(0)" ::: "memory");  // tail drain
        LOADB(1); LOADA(0, 1);
        asm volatile("s_waitcnt lgkmcnt(0)" ::: "memory");
        __builtin_amdgcn_s_barrier();
        __builtin_amdgcn_s_setprio(1); MFMA16(0); __builtin_amdgcn_s_setprio(0);
        __builtin_amdgcn_s_barrier();
        // ph3: ks1/ihalf1 + stage B(T+2,ks0)->buf
        LOADA(1, 1);
        if (T < 6) BSTAGE(T + 2, 0, buf);
        __builtin_amdgcn_s_barrier();
        __builtin_amdgcn_s_setprio(1); MFMA16(1); __builtin_amdgcn_s_setprio(0);
        __builtin_amdgcn_s_barrier();
    }

    // epilogue: acc -> LDS bf16 (ReLU, swizzled) -> coalesced dwordx4 stores
    #pragma unroll
    for (int ih = 0; ih < 8; ih++)
        #pragma unroll
        for (int j = 0; j < 4; j++)
            #pragma unroll
            for (int q = 0; q < 4; q++) {
                int row = wm * 128 + ih * 16 + (l >> 4) * 4 + q;
                int col = wn * 64 + j * 16 + (l & 15);
                float v = fmaxf(acc[ih][j][q], 0.f);
                LDSe[row * 256 + ((col >> 3) ^ (row & 7)) * 8 + (col & 7)] = (bf16)v;
            }
    asm volatile("s_waitcnt lgkmcnt(0)" ::: "memory");
    __builtin_amdgcn_s_barrier();
    #pragma unroll
    for (int i = 0; i < 16; i++) {
        int row = i * 16 + (tid >> 5);
        int cc = tid & 31;
        bf16x8 v = *(const bf16x8*)&LDSe[row * 256 + ((cc ^ (row & 7)) * 8)];
        *(bf16x8*)(C + (bm + row) * 512 + bn + cc * 8) = v;
    }
    #undef BSTAGE
    #undef AISSUE
    #undef AWRITE
}

// ---- Layers 2+3: h2 = relu(h1 @ W2) (kept in LDS), y += h2_slice @ W3 ----
__global__ __launch_bounds__(512, 2)
void k_l23(const bf16* __restrict__ A, const bf16* __restrict__ Bt,
           const bf16* __restrict__ W3t, float* __restrict__ Y) {
    __shared__ __align__(16) bf16 LDSe[65536];
    const int tid = threadIdx.x;
    const int l = tid & 63;
    const int w = tid >> 6;
    const int wm = w >> 2, wn = w & 3;
    const int l8 = l * 8;

    const int bid = blockIdx.x;
    const int logical = (bid & 7) * 64 + (bid >> 3);
    const long bm = (long)(logical >> 1) * 256;
    const int  bn = (logical & 1) * 256;

    const bf16* Asrc = A  + (bm + w * 16 + (l & 15)) * 512 + ((l >> 4) * 8);
    const bf16* Bsrc = Bt + ((long)bn + w * 16 + (l & 15)) * 512 + ((l >> 4) * 8);

    #define ASTG(TT, KS, BUF) do {                                             \
        gload_lds16(Asrc + (TT) * 64 + (KS) * 32,                              \
                    &LDSe[(BUF) * 16384 + ((w) * 2 + (KS)) * 512 + l8]);       \
        gload_lds16(Asrc + 65536 + (TT) * 64 + (KS) * 32,                      \
                    &LDSe[(BUF) * 16384 + ((8 + w) * 2 + (KS)) * 512 + l8]);   \
    } while (0)
    #define BSTG(TT, KS, BUF) do {                                             \
        gload_lds16(Bsrc + (TT) * 64 + (KS) * 32,                              \
                    &LDSe[32768 + (BUF) * 16384 + ((w) * 2 + (KS)) * 512 + l8]);\
        gload_lds16(Bsrc + 65536 + (TT) * 64 + (KS) * 32,                      \
                    &LDSe[32768 + (BUF) * 16384 + ((8 + w) * 2 + (KS)) * 512 + l8]);\
    } while (0)

    f32x4 acc[8][4];
    #pragma unroll
    for (int i = 0; i < 8; i++)
        #pragma unroll
        for (int j = 0; j < 4; j++) acc[i][j] = (f32x4){0.f, 0.f, 0.f, 0.f};
    bf16x8 afr[4], bfr[4];

    // prologue: tile0 full + tile1 ks0  (counted drain, verified round 2)
    ASTG(0, 0, 0); BSTG(0, 0, 0);
    ASTG(0, 1, 0); BSTG(0, 1, 0);
    ASTG(1, 0, 1); BSTG(1, 0, 1);
    asm volatile("s_waitcnt vmcnt(4)" ::: "memory");
    __builtin_amdgcn_s_barrier();

    for (int T = 0; T < 8; ++T) {
        const int buf = T & 1, nb = buf ^ 1;
        LOADB(0); LOADA(0, 0);
        if (T < 7) ASTG(T + 1, 1, nb);
        __builtin_amdgcn_s_barrier();
        __builtin_amdgcn_s_setprio(1); MFMA16(0); __builtin_amdgcn_s_setprio(0);
        __builtin_amdgcn_s_barrier();
        LOADA(1, 0);
        if (T < 7) BSTG(T + 1, 1, nb);
        __builtin_amdgcn_s_barrier();
        __builtin_amdgcn_s_setprio(1); MFMA16(1); __builtin_amdgcn_s_setprio(0);
        if (T < 7) { asm volatile("s_waitcnt vmcnt(8)" ::: "memory"); }
        else       { asm volatile("s_waitcnt vmcnt(0)" ::: "memory"); }
        __builtin_amdgcn_s_barrier();
        LOADB(1); LOADA(0, 1);
        if (T < 6) ASTG(T + 2, 0, buf);
        __builtin_amdgcn_s_barrier();
        __builtin_amdgcn_s_setprio(1); MFMA16(0); __builtin_amdgcn_s_setprio(0);
        __builtin_amdgcn_s_barrier();
        LOADA(1, 1);
        if (T < 6) BSTG(T + 2, 0, buf);
        __builtin_amdgcn_s_barrier();
        __builtin_amdgcn_s_setprio(1); MFMA16(1); __builtin_amdgcn_s_setprio(0);
        if (T < 6)       { asm volatile("s_waitcnt vmcnt(8)" ::: "memory"); }
        else if (T == 6) { asm volatile("s_waitcnt vmcnt(4)" ::: "memory"); }
        __builtin_amdgcn_s_barrier();
    }

    // h2 tile -> LDS (ReLU, swizzled)
    #pragma unroll
    for (int ih = 0; ih < 8; ih++)
        #pragma unroll
        for (int j = 0; j < 4; j++)
            #pragma unroll
            for (int q = 0; q < 4; q++) {
                int row = wm * 128 + ih * 16 + (l >> 4) * 4 + q;
                int col = wn * 64 + j * 16 + (l & 15);
                float v = fmaxf(acc[ih][j][q], 0.f);
                LDSe[row * 256 + ((col >> 3) ^ (row & 7)) * 8 + (col & 7)] = (bf16)v;
            }
    asm volatile("s_waitcnt lgkmcnt(0)" ::: "memory");
    __builtin_amdgcn_s_barrier();

    // layer 3 partial: y[rows][0..9] += h2[rows][bn..bn+255] @ W3t[0..15][bn..]
    bf16x8 b3[8];
    #pragma unroll
    for (int ks = 0; ks < 8; ks++)
        b3[ks] = *(const bf16x8*)(W3t + (l & 15) * 512 + bn + ks * 32 + (l >> 4) * 8);
    f32x4 yacc[2];
    yacc[0] = (f32x4){0.f, 0.f, 0.f, 0.f};
    yacc[1] = (f32x4){0.f, 0.f, 0.f, 0.f};
    #pragma unroll
    for (int fr = 0; fr < 2; fr++)
        #pragma unroll
        for (int ks = 0; ks < 8; ks++) {
            int row = w * 32 + fr * 16 + (l & 15);
            int cc = ks * 4 + (l >> 4);
            bf16x8 a3 = *(const bf16x8*)&LDSe[row * 256 + ((cc ^ (row & 7)) * 8)];
            yacc[fr] = __builtin_amdgcn_mfma_f32_16x16x32_bf16(a3, b3[ks], yacc[fr], 0, 0, 0);
        }
    if ((l & 15) < 10) {
        #pragma unroll
        for (int fr = 0; fr < 2; fr++)
            #pragma unroll
            for (int q = 0; q < 4; q++) {
                long row = bm + w * 32 + fr * 16 + (l >> 4) * 4 + q;
                atomicAdd(Y + row * 10 + (l & 15), yacc[fr][q]);
            }
    }
    #undef ASTG
    #undef BSTG
}

extern "C" void kernel_launch(void* const* d_in, const int* in_sizes, int n_in,
                              void* d_out, int out_size, void* d_ws, size_t ws_size,
                              hipStream_t stream) {
    const float* x   = (const float*)d_in[0];
    const float* mu1 = (const float*)d_in[1];
    const float* p1  = (const float*)d_in[2];
    const float* e1  = (const float*)d_in[3];
    const float* mu2 = (const float*)d_in[4];
    const float* p2  = (const float*)d_in[5];
    const float* e2  = (const float*)d_in[6];
    const float* mu3 = (const float*)d_in[7];
    const float* p3  = (const float*)d_in[8];
    const float* e3  = (const float*)d_in[9];
    float* out = (float*)d_out;

    const int B = 65536, D = 512, DO = 10, DOP = 16;

    char* ws = (char*)d_ws;
    bf16* Wt1 = (bf16*)(ws);
    bf16* Wt2 = (bf16*)(ws + 524288);
    bf16* Wt3 = (bf16*)(ws + 1048576);
    bf16* h1  = (bf16*)(ws + 1114112);

    hipLaunchKernelGGL(k_zero, dim3(512), dim3(256), 0, stream, out, out_size);
    hipLaunchKernelGGL(k_prep, dim3(256), dim3(256), 0, stream, mu1, p1, e1, Wt1, D, D,  D,   out + (long)B * DO);
    hipLaunchKernelGGL(k_prep, dim3(256), dim3(256), 0, stream, mu2, p2, e2, Wt2, D, D,  D,   out + (long)B * DO);
    hipLaunchKernelGGL(k_prep, dim3(16),  dim3(256), 0, stream, mu3, p3, e3, Wt3, D, DO, DOP, out + (long)B * DO);
    hipLaunchKernelGGL(k_l1,  dim3(512), dim3(512), 0, stream, x, Wt1, h1);
    hipLaunchKernelGGL(k_l23, dim3(512), dim3(512), 0, stream, h1, Wt2, Wt3, out);
}